// Round 1
// baseline (8815.999 us; speedup 1.0000x reference)
//
#include <hip/hip_runtime.h>
#include <math.h>

#define RR 32
#define V (RR*RR*RR)     // 32768
#define C 240
#define N 16384
#define B 8
#define K2C 480          // 2*C
#define BV 32            // voxel tile in GEMM
#define KT 32            // K tile in GEMM

// ---------------- stats: per-batch mean (3) + denom = 2*max||p-mean|| ----------------
__global__ __launch_bounds__(256) void stats_kernel(const float* __restrict__ coords,
                                                    float* __restrict__ stats) {
    int b = blockIdx.x;
    const float* cb = coords + (size_t)b * 3 * N;
    __shared__ float red[256];
    int tid = threadIdx.x;
    float m[3];
    for (int d = 0; d < 3; ++d) {
        float s = 0.f;
        for (int n = tid; n < N; n += 256) s += cb[d * N + n];
        red[tid] = s; __syncthreads();
        for (int w = 128; w > 0; w >>= 1) {
            if (tid < w) red[tid] += red[tid + w];
            __syncthreads();
        }
        m[d] = red[0] / (float)N;
        __syncthreads();
    }
    float mx = 0.f;
    for (int n = tid; n < N; n += 256) {
        float dx = cb[0 * N + n] - m[0];
        float dy = cb[1 * N + n] - m[1];
        float dz = cb[2 * N + n] - m[2];
        mx = fmaxf(mx, dx * dx + dy * dy + dz * dz);
    }
    red[tid] = mx; __syncthreads();
    for (int w = 128; w > 0; w >>= 1) {
        if (tid < w) red[tid] = fmaxf(red[tid], red[tid + w]);
        __syncthreads();
    }
    if (tid == 0) {
        stats[b * 4 + 0] = m[0];
        stats[b * 4 + 1] = m[1];
        stats[b * 4 + 2] = m[2];
        stats[b * 4 + 3] = 2.f * sqrtf(red[0]);
    }
}

// ---------------- nc (output 2) + flat voxel idx ----------------
__global__ __launch_bounds__(256) void nc_idx_kernel(const float* __restrict__ coords,
                                                     const float* __restrict__ stats,
                                                     float* __restrict__ nc_out,
                                                     int* __restrict__ idxbuf) {
    int t = blockIdx.x * 256 + threadIdx.x;   // over B*N
    int b = t >> 14;            // N = 16384
    int n = t & (N - 1);
    float denom = stats[b * 4 + 3];
    int v[3];
#pragma unroll
    for (int d = 0; d < 3; ++d) {
        float x = coords[((size_t)b * 3 + d) * N + n];
        float t0 = (x - stats[b * 4 + d]) / denom + 0.5f;
        t0 = t0 * (float)RR;
        t0 = fminf(fmaxf(t0, 0.f), (float)(RR - 1));
        nc_out[((size_t)b * 3 + d) * N + n] = t0;
        v[d] = (int)rintf(t0);   // round half to even, matches jnp.round
    }
    idxbuf[b * N + n] = v[0] * (RR * RR) + v[1] * RR + v[2];
}

// ---------------- init accumulators ----------------
__global__ __launch_bounds__(256) void init_kernel(float* __restrict__ maxbuf,
                                                   float* __restrict__ sumbuf,
                                                   unsigned* __restrict__ cnt) {
    int i = blockIdx.x * 256 + threadIdx.x;   // over V*C
    maxbuf[i] = -INFINITY;
    sumbuf[i] = 0.f;
    if (i < V) cnt[i] = 0u;
}

// ---------------- scatter: sum + max + count ----------------
__device__ __forceinline__ void atomicMaxFloat(float* addr, float val) {
    if (val >= 0.f)
        atomicMax((int*)addr, __float_as_int(val));
    else
        atomicMin((unsigned int*)addr, __float_as_uint(val));
}

__global__ __launch_bounds__(256) void scatter_kernel(const float* __restrict__ feat_b, // [C][N]
                                                      const int* __restrict__ idx_b,    // [N]
                                                      float* __restrict__ maxbuf,
                                                      float* __restrict__ sumbuf,
                                                      unsigned* __restrict__ cnt) {
    int t = blockIdx.x * 256 + threadIdx.x;   // over C*N
    int c = t >> 14;           // N = 16384
    int n = t & (N - 1);
    float f = feat_b[(size_t)c * N + n];
    int v = idx_b[n];
    atomicAdd(sumbuf + (size_t)v * C + c, f);
    atomicMaxFloat(maxbuf + (size_t)v * C + c, f);
    if (c == 0) atomicAdd(cnt + v, 1u);
}

// ---------------- GEMM + BN + swish epilogue ----------------
// fea[v][k] = k<240 ? (cnt? max : 0) : sum/max(cnt,1)   (finalize folded into staging)
// y[v][o] = sum_k fea[v][k]*w[o][k] + b[o]  -> BN -> swish -> out[o][v]
__global__ __launch_bounds__(256) void gemm_kernel(const float* __restrict__ maxbuf,
                                                   const float* __restrict__ sumbuf,
                                                   const unsigned* __restrict__ cnt,
                                                   const float* __restrict__ w,      // [240][480]
                                                   const float* __restrict__ cb,     // conv_b
                                                   const float* __restrict__ gamma,
                                                   const float* __restrict__ beta,
                                                   const float* __restrict__ mean,
                                                   const float* __restrict__ var,
                                                   float* __restrict__ out_b) {      // [240][V]
    __shared__ __align__(16) float w_s[C][KT];        // 30 KB
    __shared__ __align__(16) float fea_s[KT][BV + 1]; // padded vs bank conflicts
    __shared__ int s_flag;

    int tid = threadIdx.x;
    int v_tid = tid & 31;      // lane within 32: voxel index / k index during staging
    int o_tid = tid >> 5;      // 0..7
    int v_base = blockIdx.x * BV;

    // tile-skip: if all 32 voxels empty, fea tile is all-zero -> acc stays 0
    unsigned cv = cnt[v_base + v_tid];
    if (tid == 0) s_flag = 0;
    __syncthreads();
    if (cv != 0u) s_flag = 1;  // benign race
    __syncthreads();

    float acc[30];
#pragma unroll
    for (int j = 0; j < 30; ++j) acc[j] = 0.f;

    if (s_flag) {
        for (int k0 = 0; k0 < K2C; k0 += KT) {
            // stage w tile: 240 rows x 32 k
#pragma unroll
            for (int p = 0; p < C / 8; ++p) {
                int o = p * 8 + o_tid;
                w_s[o][v_tid] = w[(size_t)o * K2C + k0 + v_tid];
            }
            // stage fea tile (finalize on the fly)
#pragma unroll
            for (int i = 0; i < BV / 8; ++i) {
                int vl = o_tid + 8 * i;
                int vg = v_base + vl;
                int k = k0 + v_tid;
                unsigned cc = cnt[vg];
                float val;
                if (k < C) {
                    float mv = maxbuf[(size_t)vg * C + k];
                    val = cc ? mv : 0.f;
                } else {
                    val = sumbuf[(size_t)vg * C + (k - C)] / fmaxf((float)cc, 1.f);
                }
                fea_s[v_tid][vl] = val;
            }
            __syncthreads();
#pragma unroll
            for (int kk = 0; kk < KT; kk += 4) {
                float f0 = fea_s[kk + 0][v_tid];
                float f1 = fea_s[kk + 1][v_tid];
                float f2 = fea_s[kk + 2][v_tid];
                float f3 = fea_s[kk + 3][v_tid];
#pragma unroll
                for (int j = 0; j < 30; ++j) {
                    const float4 w4 = *reinterpret_cast<const float4*>(&w_s[o_tid + 8 * j][kk]);
                    acc[j] += f0 * w4.x + f1 * w4.y + f2 * w4.z + f3 * w4.w;
                }
            }
            __syncthreads();
        }
    }

    int vg = v_base + v_tid;
#pragma unroll
    for (int j = 0; j < 30; ++j) {
        int o = o_tid + 8 * j;
        float y = acc[j] + cb[o];
        float sc = gamma[o] * rsqrtf(var[o] + 1e-5f);
        y = (y - mean[o]) * sc + beta[o];
        y = y / (1.f + expf(-y));     // y * sigmoid(y)
        out_b[(size_t)o * V + vg] = y;
    }
}

extern "C" void kernel_launch(void* const* d_in, const int* in_sizes, int n_in,
                              void* d_out, int out_size, void* d_ws, size_t ws_size,
                              hipStream_t stream) {
    const float* features = (const float*)d_in[0];  // [B][C][N]
    const float* coords   = (const float*)d_in[1];  // [B][3][N]
    const float* conv_w   = (const float*)d_in[2];  // [240][480]
    const float* conv_b   = (const float*)d_in[3];
    const float* gamma    = (const float*)d_in[4];
    const float* beta     = (const float*)d_in[5];
    const float* mean     = (const float*)d_in[6];
    const float* var      = (const float*)d_in[7];

    float* out    = (float*)d_out;                    // [B][C][V]
    float* nc_out = out + (size_t)B * C * V;          // [B][3][N]

    // ws layout: idx[B*N] int | stats[B*4] f32 | maxbuf[V*C] | sumbuf[V*C] | cnt[V] u32
    char* ws = (char*)d_ws;
    int*      idxbuf = (int*)ws;
    float*    stats  = (float*)(ws + (size_t)B * N * 4);
    float*    maxbuf = (float*)(ws + (size_t)B * N * 4 + B * 4 * 4);
    float*    sumbuf = maxbuf + (size_t)V * C;
    unsigned* cnt    = (unsigned*)(sumbuf + (size_t)V * C);

    stats_kernel<<<B, 256, 0, stream>>>(coords, stats);
    nc_idx_kernel<<<(B * N) / 256, 256, 0, stream>>>(coords, stats, nc_out, idxbuf);

    for (int b = 0; b < B; ++b) {
        init_kernel<<<(V * C) / 256, 256, 0, stream>>>(maxbuf, sumbuf, cnt);
        scatter_kernel<<<(C * N) / 256, 256, 0, stream>>>(
            features + (size_t)b * C * N, idxbuf + b * N, maxbuf, sumbuf, cnt);
        gemm_kernel<<<V / BV, 256, 0, stream>>>(
            maxbuf, sumbuf, cnt, conv_w, conv_b, gamma, beta, mean, var,
            out + (size_t)b * C * V);
    }
}

// Round 2
// 1197.293 us; speedup vs baseline: 7.3633x; 7.3633x over previous
//
#include <hip/hip_runtime.h>
#include <math.h>

#define RR 32
#define V (RR*RR*RR)     // 32768
#define C 240
#define N 16384
#define B 8
#define K2C 480          // 2*C
#define NCOL 1024        // RR*RR columns, each = 32 consecutive flat voxels

typedef __attribute__((ext_vector_type(8))) short bf16x8;
typedef __attribute__((ext_vector_type(4))) float f32x4;

__device__ __forceinline__ unsigned short f2bf(float x) {
    unsigned u = __float_as_uint(x);
    u += 0x7fffu + ((u >> 16) & 1u);   // RNE (inputs are finite here)
    return (unsigned short)(u >> 16);
}

// ---------------- stats: per-batch mean (3) + denom = 2*max||p-mean|| ----------------
__global__ __launch_bounds__(256) void stats_kernel(const float* __restrict__ coords,
                                                    float* __restrict__ stats) {
    int b = blockIdx.x;
    const float* cb = coords + (size_t)b * 3 * N;
    __shared__ float red[256];
    int tid = threadIdx.x;
    float m[3];
    for (int d = 0; d < 3; ++d) {
        float s = 0.f;
        for (int n = tid; n < N; n += 256) s += cb[d * N + n];
        red[tid] = s; __syncthreads();
        for (int w = 128; w > 0; w >>= 1) {
            if (tid < w) red[tid] += red[tid + w];
            __syncthreads();
        }
        m[d] = red[0] / (float)N;
        __syncthreads();
    }
    float mx = 0.f;
    for (int n = tid; n < N; n += 256) {
        float dx = cb[0 * N + n] - m[0];
        float dy = cb[1 * N + n] - m[1];
        float dz = cb[2 * N + n] - m[2];
        mx = fmaxf(mx, dx * dx + dy * dy + dz * dz);
    }
    red[tid] = mx; __syncthreads();
    for (int w = 128; w > 0; w >>= 1) {
        if (tid < w) red[tid] = fmaxf(red[tid], red[tid + w]);
        __syncthreads();
    }
    if (tid == 0) {
        stats[b * 4 + 0] = m[0];
        stats[b * 4 + 1] = m[1];
        stats[b * 4 + 2] = m[2];
        stats[b * 4 + 3] = 2.f * sqrtf(red[0]);
    }
}

__global__ __launch_bounds__(256) void zero_hist_kernel(int* __restrict__ hist) {
    hist[blockIdx.x * 256 + threadIdx.x] = 0;   // B*NCOL = 8192
}

// ---------------- nc (output 2) + flat voxel idx + column histogram ----------------
__global__ __launch_bounds__(256) void nc_idx_kernel(const float* __restrict__ coords,
                                                     const float* __restrict__ stats,
                                                     float* __restrict__ nc_out,
                                                     int* __restrict__ idxbuf,
                                                     int* __restrict__ hist) {
    int t = blockIdx.x * 256 + threadIdx.x;   // over B*N
    int b = t >> 14;
    int n = t & (N - 1);
    float denom = stats[b * 4 + 3];
    int v[3];
#pragma unroll
    for (int d = 0; d < 3; ++d) {
        float x = coords[((size_t)b * 3 + d) * N + n];
        float t0 = (x - stats[b * 4 + d]) / denom + 0.5f;
        t0 = t0 * (float)RR;
        t0 = fminf(fmaxf(t0, 0.f), (float)(RR - 1));
        nc_out[((size_t)b * 3 + d) * N + n] = t0;
        v[d] = (int)rintf(t0);   // round half to even, matches jnp.round
    }
    int iv = v[0] * (RR * RR) + v[1] * RR + v[2];
    idxbuf[t] = iv;
    atomicAdd(hist + (b << 10) + (iv >> 5), 1);
}

// ---------------- exclusive prefix per batch over 1024 columns ----------------
__global__ __launch_bounds__(1024) void prefix_kernel(const int* __restrict__ hist,
                                                      int* __restrict__ starts,
                                                      int* __restrict__ cursor) {
    __shared__ int s[NCOL];
    int b = blockIdx.x, t = threadIdx.x;
    int v = hist[(b << 10) + t];
    s[t] = v; __syncthreads();
    for (int off = 1; off < NCOL; off <<= 1) {
        int x = (t >= off) ? s[t - off] : 0;
        __syncthreads();
        s[t] += x;
        __syncthreads();
    }
    int excl = s[t] - v;
    starts[(b << 10) + t] = excl;
    cursor[(b << 10) + t] = excl;
}

// ---------------- scatter point ids into column-sorted order ----------------
__global__ __launch_bounds__(256) void plist_kernel(const int* __restrict__ idxbuf,
                                                    int* __restrict__ cursor,
                                                    int* __restrict__ ptlist) {
    int t = blockIdx.x * 256 + threadIdx.x;   // over B*N
    int b = t >> 14;
    int n = t & (N - 1);
    int iv = idxbuf[t];
    int col = iv >> 5, z = iv & 31;
    int pos = atomicAdd(cursor + (b << 10) + col, 1);
    ptlist[(b << 14) + pos] = (n << 5) | z;
}

// ---------------- conv_w fp32 -> bf16 ----------------
__global__ __launch_bounds__(256) void wcvt_kernel(const float* __restrict__ w,
                                                   unsigned short* __restrict__ w_bf) {
    int i = blockIdx.x * 256 + threadIdx.x;   // C*K2C = 115200 exactly
    w_bf[i] = f2bf(w[i]);
}

// ---------------- features [B][C][N] -> featT [B][N][C] ----------------
__global__ __launch_bounds__(256) void transpose_kernel(const float* __restrict__ feat,
                                                        float* __restrict__ featT) {
    __shared__ float t[32][33];
    int b = blockIdx.z;
    int n0 = blockIdx.x * 32, c0 = blockIdx.y * 32;
    int tx = threadIdx.x, ty = threadIdx.y;   // 32 x 8
    const float* fb = feat + (size_t)b * C * N;
    float* fTb = featT + (size_t)b * N * C;
#pragma unroll
    for (int k = 0; k < 4; ++k) {
        int c = c0 + ty + 8 * k;
        if (c < C) t[ty + 8 * k][tx] = fb[(size_t)c * N + n0 + tx];
    }
    __syncthreads();
#pragma unroll
    for (int k = 0; k < 4; ++k) {
        int c = c0 + tx;
        int n = n0 + ty + 8 * k;
        if (c < C) fTb[(size_t)n * C + c] = t[tx][ty + 8 * k];
    }
}

// ---------------- fused per-column reduce + bf16 MFMA GEMM + BN + swish ----------------
// block = (batch, column): owns 32 voxels (z=0..31), reduces its points into LDS
// (no atomics: thread c owns channel c), then GEMM fea[32][480] x w[240][480]^T.
__global__ __launch_bounds__(256) void column_kernel(
    const float* __restrict__ fsrc,      // mode1: featT [B][N][C]; mode0: feat [B][C][N]
    const int* __restrict__ ptlist,
    const int* __restrict__ starts,
    const int* __restrict__ hist,
    const unsigned short* __restrict__ w_bf,   // [240][480]
    const float* __restrict__ cbias, const float* __restrict__ gamma,
    const float* __restrict__ beta, const float* __restrict__ mean,
    const float* __restrict__ var,
    float* __restrict__ out, int mode) {
    const int col = blockIdx.x, b = blockIdx.y;
    const int bc = (b << 10) + col;
    const int tid = threadIdx.x;
    const int pc = hist[bc];
    float* outb = out + (size_t)b * C * V;
    const int v0 = col * 32;

    __shared__ float A_s[C], B_s[C];
    if (tid < C) {
        float sc = gamma[tid] * rsqrtf(var[tid] + 1e-5f);
        A_s[tid] = sc;
        B_s[tid] = (cbias[tid] - mean[tid]) * sc + beta[tid];
    }
    __syncthreads();

    if (pc == 0) {   // empty column: constant output vector
        for (int i = tid; i < C * 32; i += 256) {
            int o = i >> 5, vv = i & 31;
            float y = B_s[o];
            y = y / (1.f + __expf(-y));
            outb[(size_t)o * V + v0 + vv] = y;
        }
        return;
    }

    __shared__ float accs[32][244];   // pad 240->244: 2-way-max LDS banks on frag reads
    __shared__ float accm[32][244];
    __shared__ float cntc[32];
    __shared__ float cinv_s[32], mask_s[32];
    __shared__ int ebuf[256];

    for (int i = tid; i < 32 * 244; i += 256) {
        ((float*)accs)[i] = 0.f;
        ((float*)accm)[i] = -INFINITY;
    }
    if (tid < 32) cntc[tid] = 0.f;
    __syncthreads();

    const int p0 = starts[bc];
    const int* pl = ptlist + (b << 14) + p0;
    const int c = tid;
    const bool act = tid < C;
    const float* fb = fsrc + (mode ? (size_t)b * N * C : (size_t)b * C * N);

    for (int pb = 0; pb < pc; pb += 256) {
        int m = min(256, pc - pb);
        __syncthreads();
        if (tid < m) ebuf[tid] = pl[pb + tid];
        __syncthreads();
#pragma unroll 4
        for (int p = 0; p < m; ++p) {
            int e = ebuf[p];
            int n = e >> 5, z = e & 31;
            if (act) {
                float f = mode ? fb[(size_t)n * C + c] : fb[(size_t)c * N + n];
                accs[z][c] += f;
                accm[z][c] = fmaxf(accm[z][c], f);
            }
            if (tid == 0) cntc[z] += 1.f;
        }
    }
    __syncthreads();
    if (tid < 32) {
        float cc = cntc[tid];
        cinv_s[tid] = 1.f / fmaxf(cc, 1.f);
        mask_s[tid] = (cc > 0.f) ? 1.f : 0.f;
    }
    __syncthreads();

    // ---- MFMA: D[o][z] = sum_k w[o][k] * fea[z][k] ----
    const int lane = tid & 63, wave = tid >> 6;
    const int nt = wave & 1;            // z-tile: 0..15 / 16..31
    const int mbase = (wave >> 1) * 8;  // channel-tile base (of 15 tiles of 16)
    const int mcnt = (wave >> 1) ? 7 : 8;
    const int z = nt * 16 + (lane & 15);
    const int koff = (lane >> 4) * 8;
    const float ci = cinv_s[z];
    const float mk = mask_s[z];

    f32x4 acc[8];
#pragma unroll
    for (int i = 0; i < 8; ++i) acc[i] = (f32x4){0.f, 0.f, 0.f, 0.f};

#pragma unroll
    for (int kc = 0; kc < 15; ++kc) {
        const int kg = kc * 32 + koff;   // aligned to 8; 240 % 8 == 0 -> no straddle
        float4 x0, x1;
        if (kg < C) {
            x0 = *(const float4*)(&accm[z][kg]);
            x1 = *(const float4*)(&accm[z][kg + 4]);
        } else {
            x0 = *(const float4*)(&accs[z][kg - C]);
            x1 = *(const float4*)(&accs[z][kg - C + 4]);
        }
        float vals[8] = {x0.x, x0.y, x0.z, x0.w, x1.x, x1.y, x1.z, x1.w};
#pragma unroll
        for (int j = 0; j < 8; ++j) {
            float v = vals[j];
            vals[j] = (kg < C) ? ((mk > 0.f) ? v : 0.f) : v * ci;
        }
        bf16x8 bfr;
#pragma unroll
        for (int j = 0; j < 8; ++j) bfr[j] = (short)f2bf(vals[j]);
        const unsigned short* wp = w_bf + (size_t)(mbase * 16 + (lane & 15)) * K2C + kc * 32 + koff;
#pragma unroll
        for (int mt = 0; mt < 8; ++mt) {
            if (mt < mcnt) {
                bf16x8 afr = *(const bf16x8*)(wp + (size_t)mt * 16 * K2C);
                acc[mt] = __builtin_amdgcn_mfma_f32_16x16x32_bf16(afr, bfr, acc[mt], 0, 0, 0);
            }
        }
    }

    const int vv = v0 + nt * 16 + (lane & 15);
    const int rbase = (lane >> 4) * 4;
#pragma unroll
    for (int mt = 0; mt < 8; ++mt) {
        if (mt < mcnt) {
#pragma unroll
            for (int r = 0; r < 4; ++r) {
                int o = (mbase + mt) * 16 + rbase + r;
                float y = acc[mt][r] * A_s[o] + B_s[o];
                y = y / (1.f + __expf(-y));
                outb[(size_t)o * V + vv] = y;
            }
        }
    }
}

extern "C" void kernel_launch(void* const* d_in, const int* in_sizes, int n_in,
                              void* d_out, int out_size, void* d_ws, size_t ws_size,
                              hipStream_t stream) {
    const float* features = (const float*)d_in[0];  // [B][C][N]
    const float* coords   = (const float*)d_in[1];  // [B][3][N]
    const float* conv_w   = (const float*)d_in[2];  // [240][480]
    const float* conv_b   = (const float*)d_in[3];
    const float* gamma    = (const float*)d_in[4];
    const float* beta     = (const float*)d_in[5];
    const float* mean     = (const float*)d_in[6];
    const float* var      = (const float*)d_in[7];

    float* out    = (float*)d_out;                    // [B][C][V]
    float* nc_out = out + (size_t)B * C * V;          // [B][3][N]

    char* ws = (char*)d_ws;
    size_t off = 0;
    auto carve = [&](size_t bytes) { char* p = ws + off; off += (bytes + 255) & ~(size_t)255; return p; };
    int*            idxbuf = (int*)carve((size_t)B * N * 4);
    float*          stats  = (float*)carve(B * 4 * 4);
    unsigned short* w_bf   = (unsigned short*)carve((size_t)C * K2C * 2);
    int*            hist   = (int*)carve(B * NCOL * 4);
    int*            starts = (int*)carve(B * NCOL * 4);
    int*            cursor = (int*)carve(B * NCOL * 4);
    int*            ptlist = (int*)carve((size_t)B * N * 4);
    size_t featT_off = off;
    float*          featT  = (float*)carve((size_t)B * N * C * 4);
    // mode 1: transpose features for coalesced per-point gathers (needs ~128 MB ws)
    const int mode = (ws_size >= off) ? 1 : 0;

    stats_kernel<<<B, 256, 0, stream>>>(coords, stats);
    zero_hist_kernel<<<B * NCOL / 256, 256, 0, stream>>>(hist);
    nc_idx_kernel<<<(B * N) / 256, 256, 0, stream>>>(coords, stats, nc_out, idxbuf, hist);
    prefix_kernel<<<B, NCOL, 0, stream>>>(hist, starts, cursor);
    plist_kernel<<<(B * N) / 256, 256, 0, stream>>>(idxbuf, cursor, ptlist);
    wcvt_kernel<<<(C * K2C) / 256, 256, 0, stream>>>(conv_w, w_bf);
    if (mode) {
        transpose_kernel<<<dim3(N / 32, 8, B), dim3(32, 8), 0, stream>>>(features, featT);
    }
    column_kernel<<<dim3(NCOL, B), 256, 0, stream>>>(
        mode ? featT : features, ptlist, starts, hist, w_bf,
        conv_b, gamma, beta, mean, var, out, mode);
    (void)featT_off; (void)in_sizes; (void)n_in; (void)out_size;
}

// Round 3
// 790.264 us; speedup vs baseline: 11.1558x; 1.5151x over previous
//
#include <hip/hip_runtime.h>
#include <math.h>

#define RR 32
#define V 32768          // RR^3
#define C 240
#define N 16384
#define B 8
#define K2C 480          // 2*C
#define NCOL 1024        // RR*RR columns of 32 voxels
#define FPAD 488         // fea_s row stride (bf16): 488 -> 2-way-max bank pattern

typedef __attribute__((ext_vector_type(8))) short bf16x8;
typedef __attribute__((ext_vector_type(4))) float f32x4;

__device__ __forceinline__ unsigned short f2bf(float x) {
    unsigned u = __float_as_uint(x);
    u += 0x7fffu + ((u >> 16) & 1u);   // RNE, finite inputs
    return (unsigned short)(u >> 16);
}
__device__ __forceinline__ float bf2f(unsigned short u) {
    return __uint_as_float(((unsigned)u) << 16);
}

// ---------- stats stage 1: per-(batch,chunk) coordinate sums (deterministic) ----------
__global__ __launch_bounds__(256) void stats1_kernel(const float* __restrict__ coords,
                                                     float* __restrict__ psum) {
    int b = blockIdx.y, ch = blockIdx.x;          // 16 chunks of 1024 points
    const float* cb = coords + (size_t)b * 3 * N;
    int tid = threadIdx.x, n0 = ch * 1024;
    __shared__ float red[256];
    for (int d = 0; d < 3; ++d) {
        float s = 0.f;
        for (int i = tid; i < 1024; i += 256) s += cb[d * N + n0 + i];
        red[tid] = s; __syncthreads();
        for (int w = 128; w > 0; w >>= 1) { if (tid < w) red[tid] += red[tid + w]; __syncthreads(); }
        if (tid == 0) psum[(b * 16 + ch) * 3 + d] = red[0];
        __syncthreads();
    }
}

// ---------- stats stage 2: max dist^2 via exact int atomicMax (order-safe) ----------
__global__ __launch_bounds__(256) void stats2_kernel(const float* __restrict__ coords,
                                                     const float* __restrict__ psum,
                                                     int* __restrict__ smax) {
    int b = blockIdx.y, ch = blockIdx.x;
    float m[3];
    for (int d = 0; d < 3; ++d) {
        float s = 0.f;
        for (int j = 0; j < 16; ++j) s += psum[(b * 16 + j) * 3 + d];  // fixed order
        m[d] = s / (float)N;
    }
    const float* cb = coords + (size_t)b * 3 * N;
    int tid = threadIdx.x, n0 = ch * 1024;
    float mx = 0.f;
    for (int i = tid; i < 1024; i += 256) {
        float dx = cb[0 * N + n0 + i] - m[0];
        float dy = cb[1 * N + n0 + i] - m[1];
        float dz = cb[2 * N + n0 + i] - m[2];
        mx = fmaxf(mx, dx * dx + dy * dy + dz * dz);
    }
    __shared__ float red[256];
    red[tid] = mx; __syncthreads();
    for (int w = 128; w > 0; w >>= 1) { if (tid < w) red[tid] = fmaxf(red[tid], red[tid + w]); __syncthreads(); }
    if (tid == 0) atomicMax(smax + b, __float_as_int(red[0]));   // values >= 0
}

// ---------- stats stage 3: finalize mean + denom ----------
__global__ void stats3_kernel(const float* __restrict__ psum, const int* __restrict__ smax,
                              float* __restrict__ stats) {
    int b = threadIdx.x;
    if (b < B) {
        for (int d = 0; d < 3; ++d) {
            float s = 0.f;
            for (int j = 0; j < 16; ++j) s += psum[(b * 16 + j) * 3 + d];  // same fixed order
            stats[b * 4 + d] = s / (float)N;
        }
        stats[b * 4 + 3] = 2.f * sqrtf(__int_as_float(smax[b]));
    }
}

// ---------- nc (output 2) + flat voxel idx + per-voxel histogram ----------
__global__ __launch_bounds__(256) void nc_idx_kernel(const float* __restrict__ coords,
                                                     const float* __restrict__ stats,
                                                     float* __restrict__ nc_out,
                                                     int* __restrict__ idxbuf,
                                                     int* __restrict__ hist) {
    int t = blockIdx.x * 256 + threadIdx.x;   // over B*N
    int b = t >> 14;
    int n = t & (N - 1);
    float denom = stats[b * 4 + 3];
    int v[3];
#pragma unroll
    for (int d = 0; d < 3; ++d) {
        float x = coords[((size_t)b * 3 + d) * N + n];
        float t0 = (x - stats[b * 4 + d]) / denom + 0.5f;
        t0 = t0 * (float)RR;
        t0 = fminf(fmaxf(t0, 0.f), (float)(RR - 1));
        nc_out[((size_t)b * 3 + d) * N + n] = t0;
        v[d] = (int)rintf(t0);   // round half to even == jnp.round
    }
    int iv = v[0] * (RR * RR) + v[1] * RR + v[2];
    idxbuf[t] = iv;
    atomicAdd(hist + b * V + iv, 1);
}

// ---------- exclusive prefix over V=32768 voxels per batch ----------
__global__ __launch_bounds__(1024) void prefix_kernel(const int* __restrict__ hist,
                                                      int* __restrict__ starts,
                                                      int* __restrict__ cursor) {
    __shared__ int part[1024];
    int b = blockIdx.x, t = threadIdx.x;
    int base = b * V + t * 32;
    int s = 0;
    for (int j = 0; j < 32; ++j) s += hist[base + j];
    part[t] = s; __syncthreads();
    for (int off = 1; off < 1024; off <<= 1) {
        int x = (t >= off) ? part[t - off] : 0;
        __syncthreads();
        part[t] += x;
        __syncthreads();
    }
    int run = part[t] - s;   // exclusive
    for (int j = 0; j < 32; ++j) {
        int h = hist[base + j];
        starts[base + j] = run;
        cursor[base + j] = run;
        run += h;
    }
}

// ---------- scatter point ids into voxel-sorted order ----------
__global__ __launch_bounds__(256) void plist_kernel(const int* __restrict__ idxbuf,
                                                    int* __restrict__ cursor,
                                                    int* __restrict__ ptlist) {
    int t = blockIdx.x * 256 + threadIdx.x;   // over B*N
    int b = t >> 14;
    int n = t & (N - 1);
    int iv = idxbuf[t];
    int pos = atomicAdd(cursor + b * V + iv, 1);
    ptlist[(b << 14) + pos] = (n << 5) | (iv & 31);
}

// ---------- conv_w fp32 -> bf16 ----------
__global__ __launch_bounds__(256) void wcvt_kernel(const float* __restrict__ w,
                                                   unsigned short* __restrict__ w_bf) {
    int i = blockIdx.x * 256 + threadIdx.x;   // C*K2C = 115200
    w_bf[i] = f2bf(w[i]);
}

// ---------- features [B][C][N] fp32 -> featT [B][N][C] bf16 ----------
__global__ __launch_bounds__(256) void transpose_kernel(const float* __restrict__ feat,
                                                        unsigned short* __restrict__ featT) {
    __shared__ float t[32][33];
    int b = blockIdx.z;
    int n0 = blockIdx.x * 32, c0 = blockIdx.y * 32;
    int tx = threadIdx.x, ty = threadIdx.y;   // 32 x 8
    const float* fb = feat + (size_t)b * C * N;
    unsigned short* fTb = featT + (size_t)b * N * C;
#pragma unroll
    for (int k = 0; k < 4; ++k) {
        int c = c0 + ty + 8 * k;
        if (c < C) t[ty + 8 * k][tx] = fb[(size_t)c * N + n0 + tx];
    }
    __syncthreads();
#pragma unroll
    for (int k = 0; k < 4; ++k) {
        int c = c0 + tx;
        int n = n0 + ty + 8 * k;
        if (c < C) fTb[(size_t)n * C + c] = f2bf(t[tx][ty + 8 * k]);
    }
}

// ---------- fused per-column register-reduce + bf16 MFMA + BN + swish ----------
__global__ __launch_bounds__(256) void column_kernel(
    const unsigned short* __restrict__ featT,   // mode1: [B][N][C] bf16
    const float* __restrict__ feat,             // mode0: [B][C][N] fp32
    const int mode,
    const int* __restrict__ ptlist,
    const int* __restrict__ starts,
    const int* __restrict__ hist,
    const unsigned short* __restrict__ w_bf,    // [240][480] bf16
    const float* __restrict__ cbias, const float* __restrict__ gamma,
    const float* __restrict__ beta, const float* __restrict__ mean,
    const float* __restrict__ var,
    float* __restrict__ out) {
    const int col = blockIdx.x, b = blockIdx.y;
    const int tid = threadIdx.x;
    const int v0 = col * 32;
    float* outb = out + (size_t)b * C * V;

    __shared__ float A_s[C], B_s[C];
    __shared__ unsigned short fea_s[32][FPAD];   // [z][k]: k<240 max, k>=240 avg (bf16)
    __shared__ int cnt_s[32];
    __shared__ float cinv_s[32];

    if (tid < C) {
        float sc = gamma[tid] * rsqrtf(var[tid] + 1e-5f);
        A_s[tid] = sc;
        B_s[tid] = (cbias[tid] - mean[tid]) * sc + beta[tid];
    }
    if (tid < 32) {
        int k = hist[b * V + v0 + tid];
        cnt_s[tid] = k;
        cinv_s[tid] = 1.f / (float)(k > 0 ? k : 1);
    }
    __syncthreads();

    int pc = 0;
#pragma unroll
    for (int z = 0; z < 32; ++z) pc += cnt_s[z];

    if (pc == 0) {   // empty column: constant output vector
        for (int i = tid; i < C * 32; i += 256) {
            int o = i >> 5, vv = i & 31;
            float y = B_s[o];
            y = y / (1.f + __expf(-y));
            outb[(size_t)o * V + v0 + vv] = y;
        }
        return;
    }

    // zero fea (covers empty voxels: max->0, avg->0)
    for (int i = tid; i < 32 * FPAD / 2; i += 256) ((unsigned*)fea_s)[i] = 0u;
    __syncthreads();

    // ---- register reduction over voxel-sorted points ----
    const int c = (tid < C) ? tid : 0;
    const bool act = tid < C;
    int pos = starts[b * V + v0];
    const int* pl = ptlist + (b << 14);
    const unsigned short* fT = featT + (size_t)b * N * C;
    const float* fF = feat + (size_t)b * C * N;

    for (int z = 0; z < 32; ++z) {
        int k = cnt_s[z];
        if (k == 0) continue;
        float s = 0.f, mx = -INFINITY;
        int i = 0;
        for (; i + 8 <= k; i += 8) {
            int n_[8]; float f_[8];
#pragma unroll
            for (int j = 0; j < 8; ++j) n_[j] = pl[pos + i + j] >> 5;
#pragma unroll
            for (int j = 0; j < 8; ++j)
                f_[j] = mode ? bf2f(fT[n_[j] * C + c]) : fF[(size_t)c * N + n_[j]];
#pragma unroll
            for (int j = 0; j < 8; ++j) { s += f_[j]; mx = fmaxf(mx, f_[j]); }
        }
        for (; i < k; ++i) {
            int n = pl[pos + i] >> 5;
            float f = mode ? bf2f(fT[n * C + c]) : fF[(size_t)c * N + n];
            s += f; mx = fmaxf(mx, f);
        }
        if (act) {
            fea_s[z][c] = f2bf(mx);
            fea_s[z][C + c] = f2bf(s / (float)k);   // IEEE divide, matches ref
        }
        pos += k;
    }
    __syncthreads();

    // ---- MFMA: D[o][z] = sum_k w[o][k] * fea[z][k] ----
    const int lane = tid & 63, wave = tid >> 6;
    const int nt = wave & 1;            // z half
    const int mbase = (wave >> 1) * 8;  // o-tile base (15 tiles of 16)
    const int mcnt = (wave >> 1) ? 7 : 8;
    const int zl = nt * 16 + (lane & 15);
    const int koff = (lane >> 4) * 8;

    f32x4 acc[8];
#pragma unroll
    for (int i = 0; i < 8; ++i) acc[i] = (f32x4){0.f, 0.f, 0.f, 0.f};

#pragma unroll
    for (int kc = 0; kc < 15; ++kc) {
        const int kg = kc * 32 + koff;
        bf16x8 bfr = *(const bf16x8*)&fea_s[zl][kg];
        const unsigned short* wp = w_bf + (size_t)(mbase * 16 + (lane & 15)) * K2C + kg;
#pragma unroll
        for (int mt = 0; mt < 8; ++mt) {
            if (mt < mcnt) {
                bf16x8 afr = *(const bf16x8*)(wp + (size_t)mt * 16 * K2C);
                acc[mt] = __builtin_amdgcn_mfma_f32_16x16x32_bf16(afr, bfr, acc[mt], 0, 0, 0);
            }
        }
    }

    const int vv = v0 + zl;
    const int rbase = (lane >> 4) * 4;
#pragma unroll
    for (int mt = 0; mt < 8; ++mt) {
        if (mt < mcnt) {
#pragma unroll
            for (int r = 0; r < 4; ++r) {
                int o = (mbase + mt) * 16 + rbase + r;
                float y = acc[mt][r] * A_s[o] + B_s[o];
                y = y / (1.f + __expf(-y));
                outb[(size_t)o * V + vv] = y;
            }
        }
    }
}

extern "C" void kernel_launch(void* const* d_in, const int* in_sizes, int n_in,
                              void* d_out, int out_size, void* d_ws, size_t ws_size,
                              hipStream_t stream) {
    const float* features = (const float*)d_in[0];  // [B][C][N]
    const float* coords   = (const float*)d_in[1];  // [B][3][N]
    const float* conv_w   = (const float*)d_in[2];  // [240][480]
    const float* conv_b   = (const float*)d_in[3];
    const float* gamma    = (const float*)d_in[4];
    const float* beta     = (const float*)d_in[5];
    const float* mean     = (const float*)d_in[6];
    const float* var      = (const float*)d_in[7];

    float* out    = (float*)d_out;                    // [B][C][V]
    float* nc_out = out + (size_t)B * C * V;          // [B][3][N]

    char* ws = (char*)d_ws;
    size_t off = 0;
    auto carve = [&](size_t bytes) { char* p = ws + off; off += (bytes + 255) & ~(size_t)255; return p; };
    int*            hist   = (int*)carve((size_t)B * V * 4);          // 1 MB
    int*            smax   = (int*)carve(B * 4);
    float*          psum   = (float*)carve(B * 16 * 3 * 4);
    float*          stats  = (float*)carve(B * 4 * 4);
    int*            idxbuf = (int*)carve((size_t)B * N * 4);
    int*            starts = (int*)carve((size_t)B * V * 4);
    int*            cursor = (int*)carve((size_t)B * V * 4);
    int*            ptlist = (int*)carve((size_t)B * N * 4);
    unsigned short* w_bf   = (unsigned short*)carve((size_t)C * K2C * 2);
    unsigned short* featT  = (unsigned short*)carve((size_t)B * N * C * 2);  // 63 MB
    const int mode = (ws_size >= off) ? 1 : 0;

    // zero hist + smax (contiguous carve region)
    hipMemsetAsync(hist, 0, (size_t)((char*)psum - (char*)hist), stream);

    stats1_kernel<<<dim3(16, B), 256, 0, stream>>>(coords, psum);
    stats2_kernel<<<dim3(16, B), 256, 0, stream>>>(coords, psum, smax);
    stats3_kernel<<<1, 64, 0, stream>>>(psum, smax, stats);
    nc_idx_kernel<<<(B * N) / 256, 256, 0, stream>>>(coords, stats, nc_out, idxbuf, hist);
    prefix_kernel<<<B, 1024, 0, stream>>>(hist, starts, cursor);
    plist_kernel<<<(B * N) / 256, 256, 0, stream>>>(idxbuf, cursor, ptlist);
    wcvt_kernel<<<(C * K2C) / 256, 256, 0, stream>>>(conv_w, w_bf);
    if (mode) {
        transpose_kernel<<<dim3(N / 32, 8, B), dim3(32, 8), 0, stream>>>(features, featT);
    }
    column_kernel<<<dim3(NCOL, B), 256, 0, stream>>>(
        featT, features, mode, ptlist, starts, hist, w_bf,
        conv_b, gamma, beta, mean, var, out);
    (void)in_sizes; (void)n_in; (void)out_size;
}

// Round 5
// 648.709 us; speedup vs baseline: 13.5901x; 1.2182x over previous
//
#include <hip/hip_runtime.h>
#include <math.h>

#define RR 32
#define V 32768          // RR^3
#define C 240
#define N 16384
#define B 8
#define K2C 480          // 2*C
#define NCOL 1024        // RR*RR columns of 32 voxels
#define FPAD 488         // fea_s row stride (bf16): 488*2/4 %32 -> 2-way banks (free)
#define EBUF 512         // staged point entries per round

typedef __attribute__((ext_vector_type(8))) short bf16x8;
typedef __attribute__((ext_vector_type(4))) float f32x4;

__device__ __forceinline__ unsigned short f2bf(float x) {
    unsigned u = __float_as_uint(x);
    u += 0x7fffu + ((u >> 16) & 1u);   // RNE, finite inputs
    return (unsigned short)(u >> 16);
}
__device__ __forceinline__ float bf2f(unsigned short u) {
    return __uint_as_float(((unsigned)u) << 16);
}

// ---------- fused stats: per-batch mean (3) + denom = 2*max||p-mean|| ----------
__global__ __launch_bounds__(1024) void stats_kernel(const float* __restrict__ coords,
                                                     float* __restrict__ stats) {
    int b = blockIdx.x, tid = threadIdx.x;
    const float* cb = coords + (size_t)b * 3 * N;
    __shared__ float red[1024];
    float m[3];
    for (int d = 0; d < 3; ++d) {
        float s = 0.f;
        for (int n = tid; n < N; n += 1024) s += cb[d * N + n];
        red[tid] = s; __syncthreads();
        for (int w = 512; w > 0; w >>= 1) { if (tid < w) red[tid] += red[tid + w]; __syncthreads(); }
        m[d] = red[0] / (float)N;
        __syncthreads();
    }
    float mx = 0.f;
    for (int n = tid; n < N; n += 1024) {
        float dx = cb[0 * N + n] - m[0];
        float dy = cb[1 * N + n] - m[1];
        float dz = cb[2 * N + n] - m[2];
        mx = fmaxf(mx, dx * dx + dy * dy + dz * dz);
    }
    red[tid] = mx; __syncthreads();
    for (int w = 512; w > 0; w >>= 1) { if (tid < w) red[tid] = fmaxf(red[tid], red[tid + w]); __syncthreads(); }
    if (tid == 0) {
        stats[b * 4 + 0] = m[0];
        stats[b * 4 + 1] = m[1];
        stats[b * 4 + 2] = m[2];
        stats[b * 4 + 3] = 2.f * sqrtf(red[0]);
    }
}

// ---------- nc (output 2) + flat voxel idx + per-voxel histogram ----------
__global__ __launch_bounds__(256) void nc_idx_kernel(const float* __restrict__ coords,
                                                     const float* __restrict__ stats,
                                                     float* __restrict__ nc_out,
                                                     int* __restrict__ idxbuf,
                                                     int* __restrict__ hist) {
    int t = blockIdx.x * 256 + threadIdx.x;   // over B*N
    int b = t >> 14;
    int n = t & (N - 1);
    float denom = stats[b * 4 + 3];
    int v[3];
#pragma unroll
    for (int d = 0; d < 3; ++d) {
        float x = coords[((size_t)b * 3 + d) * N + n];
        float t0 = (x - stats[b * 4 + d]) / denom + 0.5f;
        t0 = t0 * (float)RR;
        t0 = fminf(fmaxf(t0, 0.f), (float)(RR - 1));
        nc_out[((size_t)b * 3 + d) * N + n] = t0;
        v[d] = (int)rintf(t0);   // round half to even == jnp.round
    }
    int iv = v[0] * (RR * RR) + v[1] * RR + v[2];
    idxbuf[t] = iv;
    atomicAdd(hist + b * V + iv, 1);
}

// ---------- exclusive prefix over V=32768 voxels per batch ----------
__global__ __launch_bounds__(1024) void prefix_kernel(const int* __restrict__ hist,
                                                      int* __restrict__ starts,
                                                      int* __restrict__ cursor) {
    __shared__ int part[1024];
    int b = blockIdx.x, t = threadIdx.x;
    int base = b * V + t * 32;
    int s = 0;
    for (int j = 0; j < 32; ++j) s += hist[base + j];
    part[t] = s; __syncthreads();
    for (int off = 1; off < 1024; off <<= 1) {
        int x = (t >= off) ? part[t - off] : 0;
        __syncthreads();
        part[t] += x;
        __syncthreads();
    }
    int run = part[t] - s;   // exclusive
    for (int j = 0; j < 32; ++j) {
        int h = hist[base + j];
        starts[base + j] = run;
        cursor[base + j] = run;
        run += h;
    }
}

// ---------- scatter point ids into voxel-sorted order ----------
__global__ __launch_bounds__(256) void plist_kernel(const int* __restrict__ idxbuf,
                                                    int* __restrict__ cursor,
                                                    int* __restrict__ ptlist) {
    int t = blockIdx.x * 256 + threadIdx.x;   // over B*N
    int b = t >> 14;
    int n = t & (N - 1);
    int iv = idxbuf[t];
    int pos = atomicAdd(cursor + b * V + iv, 1);
    ptlist[(b << 14) + pos] = (n << 5) | (iv & 31);
}

// ---------- conv_w fp32 -> bf16 ----------
__global__ __launch_bounds__(256) void wcvt_kernel(const float* __restrict__ w,
                                                   unsigned short* __restrict__ w_bf) {
    int i = blockIdx.x * 256 + threadIdx.x;   // C*K2C = 115200
    w_bf[i] = f2bf(w[i]);
}

// ---------- features [B][C][N] fp32 -> featT [B][N][C] bf16 (uint-packed stores) ----------
__global__ __launch_bounds__(256) void transpose_kernel(const float* __restrict__ feat,
                                                        unsigned short* __restrict__ featT) {
    __shared__ float t[32][33];
    int b = blockIdx.z;
    int n0 = blockIdx.x * 32, c0 = blockIdx.y * 32;
    int l = threadIdx.x;          // 256 linear threads
    int tx = l & 31, ty = l >> 5; // 32 x 8
    const float* fb = feat + (size_t)b * C * N;
    unsigned short* fTb = featT + (size_t)b * N * C;
#pragma unroll
    for (int k = 0; k < 4; ++k) {
        int c = c0 + ty + 8 * k;
        if (c < C) t[ty + 8 * k][tx] = fb[(size_t)c * N + n0 + tx];
    }
    __syncthreads();
    int cp = l & 15;   // c-pair index
    int nl = l >> 4;   // 16 n-rows per pass
#pragma unroll
    for (int k = 0; k < 2; ++k) {
        int n = n0 + nl + 16 * k;
        int c = c0 + 2 * cp;
        if (c < C) {
            unsigned lo = f2bf(t[2 * cp][nl + 16 * k]);
            unsigned hi = f2bf(t[2 * cp + 1][nl + 16 * k]);
            *(unsigned*)&fTb[(size_t)n * C + c] = lo | (hi << 16);
        }
    }
}

// ---------- fused per-column pipelined reduce + bf16 MFMA + BN + swish ----------
__global__ __launch_bounds__(256) void column_kernel(
    const unsigned short* __restrict__ featT,   // [B][N][C] bf16
    const int* __restrict__ ptlist,
    const int* __restrict__ starts,
    const int* __restrict__ hist,
    const unsigned short* __restrict__ w_bf,    // [240][480] bf16
    const float* __restrict__ cbias, const float* __restrict__ gamma,
    const float* __restrict__ beta, const float* __restrict__ mean,
    const float* __restrict__ var,
    float* __restrict__ out) {
    const int col = blockIdx.x, b = blockIdx.y;
    const int tid = threadIdx.x;
    const int v0 = col * 32;
    float* outb = out + (size_t)b * C * V;

    __shared__ float A_s[C], B_s[C];
    __shared__ unsigned short fea_s[32][FPAD];   // [z][k]: k<240 max, k>=240 avg (bf16)
    __shared__ int cnt_s[32];
    __shared__ int ebuf[EBUF];

    if (tid < C) {
        float sc = gamma[tid] * rsqrtf(var[tid] + 1e-5f);
        A_s[tid] = sc;
        B_s[tid] = (cbias[tid] - mean[tid]) * sc + beta[tid];
    }
    if (tid < 32) cnt_s[tid] = hist[b * V + v0 + tid];
    __syncthreads();

    int pc = 0;
#pragma unroll
    for (int z = 0; z < 32; ++z) pc += cnt_s[z];

    if (pc == 0) {   // empty column: constant output vector
        for (int i = tid; i < C * 32; i += 256) {
            int o = i >> 5, vv = i & 31;
            float y = B_s[o];
            y = y / (1.f + __expf(-y));
            outb[(size_t)o * V + v0 + vv] = y;
        }
        return;
    }

    // zero fea (covers empty voxels: max->0, avg->0)
    for (int i = tid; i < 32 * FPAD / 2; i += 256) ((unsigned*)fea_s)[i] = 0u;

    const int c = (tid < C) ? tid : 0;
    const bool act = tid < C;
    const int pos = starts[b * V + v0];
    const int* pl = ptlist + (b << 14) + pos;
    const unsigned short* fT = featT + (size_t)b * N * C;

    // ---- pipelined stream over ALL points of the column (sorted by z) ----
    float s = 0.f, mx = -INFINITY;
    int curz = -1;
    for (int base = 0; base < pc; base += EBUF) {
        int mm = min(EBUF, pc - base);
        __syncthreads();
        for (int i = tid; i < mm; i += 256) ebuf[i] = pl[base + i];   // coalesced stage
        __syncthreads();
        for (int i0 = 0; i0 < mm; i0 += 16) {
            int m = min(16, mm - i0);
            int e_[16];
#pragma unroll
            for (int j = 0; j < 16; ++j) e_[j] = ebuf[i0 + ((j < m) ? j : m - 1)];
            float f_[16];
#pragma unroll
            for (int j = 0; j < 16; ++j) f_[j] = bf2f(fT[(e_[j] >> 5) * C + c]);
#pragma unroll
            for (int j = 0; j < 16; ++j) {
                if (j < m) {
                    int zj = e_[j] & 31;                 // block-uniform
                    if (zj != curz) {                    // uniform branch
                        if (curz >= 0 && act) {
                            fea_s[curz][c] = f2bf(mx);
                            fea_s[curz][C + c] = f2bf(s / (float)cnt_s[curz]);
                        }
                        curz = zj; s = 0.f; mx = -INFINITY;
                    }
                    s += f_[j]; mx = fmaxf(mx, f_[j]);
                }
            }
        }
    }
    if (curz >= 0 && act) {
        fea_s[curz][c] = f2bf(mx);
        fea_s[curz][C + c] = f2bf(s / (float)cnt_s[curz]);
    }
    __syncthreads();

    // ---- MFMA: D[o][z] = sum_k w[o][k] * fea[z][k] ----
    const int lane = tid & 63, wave = tid >> 6;
    const int nt = wave & 1;            // z half
    const int mbase = (wave >> 1) * 8;  // o-tile base (15 tiles of 16)
    const int mcnt = (wave >> 1) ? 7 : 8;
    const int zl = nt * 16 + (lane & 15);
    const int koff = (lane >> 4) * 8;

    f32x4 acc[8];
#pragma unroll
    for (int i = 0; i < 8; ++i) acc[i] = (f32x4){0.f, 0.f, 0.f, 0.f};

#pragma unroll
    for (int kc = 0; kc < 15; ++kc) {
        const int kg = kc * 32 + koff;
        bf16x8 bfr = *(const bf16x8*)&fea_s[zl][kg];
        const unsigned short* wp = w_bf + (size_t)(mbase * 16 + (lane & 15)) * K2C + kg;
#pragma unroll
        for (int mt = 0; mt < 8; ++mt) {
            if (mt < mcnt) {
                bf16x8 afr = *(const bf16x8*)(wp + (size_t)mt * 16 * K2C);
                acc[mt] = __builtin_amdgcn_mfma_f32_16x16x32_bf16(afr, bfr, acc[mt], 0, 0, 0);
            }
        }
    }

    const int vv = v0 + zl;
    const int rbase = (lane >> 4) * 4;
#pragma unroll
    for (int mt = 0; mt < 8; ++mt) {
        if (mt < mcnt) {
#pragma unroll
            for (int r = 0; r < 4; ++r) {
                int o = (mbase + mt) * 16 + rbase + r;
                float y = acc[mt][r] * A_s[o] + B_s[o];
                y = y / (1.f + __expf(-y));
                outb[(size_t)o * V + vv] = y;
            }
        }
    }
}

extern "C" void kernel_launch(void* const* d_in, const int* in_sizes, int n_in,
                              void* d_out, int out_size, void* d_ws, size_t ws_size,
                              hipStream_t stream) {
    const float* features = (const float*)d_in[0];  // [B][C][N]
    const float* coords   = (const float*)d_in[1];  // [B][3][N]
    const float* conv_w   = (const float*)d_in[2];  // [240][480]
    const float* conv_b   = (const float*)d_in[3];
    const float* gamma    = (const float*)d_in[4];
    const float* beta     = (const float*)d_in[5];
    const float* mean     = (const float*)d_in[6];
    const float* var      = (const float*)d_in[7];

    float* out    = (float*)d_out;                    // [B][C][V]
    float* nc_out = out + (size_t)B * C * V;          // [B][3][N]

    char* ws = (char*)d_ws;
    size_t off = 0;
    auto carve = [&](size_t bytes) { char* p = ws + off; off += (bytes + 255) & ~(size_t)255; return p; };
    int*            hist   = (int*)carve((size_t)B * V * 4);          // 1 MB
    float*          stats  = (float*)carve(B * 4 * 4);
    int*            idxbuf = (int*)carve((size_t)B * N * 4);
    int*            starts = (int*)carve((size_t)B * V * 4);
    int*            cursor = (int*)carve((size_t)B * V * 4);
    int*            ptlist = (int*)carve((size_t)B * N * 4);
    unsigned short* w_bf   = (unsigned short*)carve((size_t)C * K2C * 2);
    unsigned short* featT  = (unsigned short*)carve((size_t)B * N * C * 2);  // 63 MB
    (void)off;

    hipMemsetAsync(hist, 0, (size_t)B * V * 4, stream);

    stats_kernel<<<B, 1024, 0, stream>>>(coords, stats);
    nc_idx_kernel<<<(B * N) / 256, 256, 0, stream>>>(coords, stats, nc_out, idxbuf, hist);
    prefix_kernel<<<B, 1024, 0, stream>>>(hist, starts, cursor);
    plist_kernel<<<(B * N) / 256, 256, 0, stream>>>(idxbuf, cursor, ptlist);
    wcvt_kernel<<<(C * K2C) / 256, 256, 0, stream>>>(conv_w, w_bf);
    transpose_kernel<<<dim3(N / 32, 8, B), 256, 0, stream>>>(features, featT);
    column_kernel<<<dim3(NCOL, B), 256, 0, stream>>>(
        featT, ptlist, starts, hist, w_bf,
        conv_b, gamma, beta, mean, var, out);
    (void)in_sizes; (void)n_in; (void)out_size;
}

// Round 6
// 639.795 us; speedup vs baseline: 13.7794x; 1.0139x over previous
//
#include <hip/hip_runtime.h>
#include <math.h>

#define RR 32
#define V 32768          // RR^3
#define C 240
#define N 16384
#define B 8
#define K2C 480          // 2*C
#define NCOL 1024        // RR*RR columns of 32 voxels
#define FPAD 488         // fea_s row stride (bf16)
#define EBUF 512         // staged point entries per round

typedef __attribute__((ext_vector_type(8))) short bf16x8;
typedef __attribute__((ext_vector_type(4))) float f32x4;

__device__ __forceinline__ unsigned short f2bf(float x) {
    unsigned u = __float_as_uint(x);
    u += 0x7fffu + ((u >> 16) & 1u);   // RNE, finite inputs
    return (unsigned short)(u >> 16);
}

// ---------- fused: hist zero + conv_w->bf16 + per-batch mean/denom ----------
__global__ __launch_bounds__(1024) void stats_kernel(const float* __restrict__ coords,
                                                     float* __restrict__ stats,
                                                     int* __restrict__ hist,
                                                     const float* __restrict__ w,
                                                     unsigned short* __restrict__ w_bf) {
    int b = blockIdx.x, tid = threadIdx.x;
    // zero this batch's hist slice (V ints) with int4 stores
    int4 z4 = {0, 0, 0, 0};
    int4* hz = (int4*)(hist + b * V);
    for (int i = tid; i < V / 4; i += 1024) hz[i] = z4;
    // conv_w convert: 115200 / 8 blocks = 14400 each
    for (int i = tid; i < 14400; i += 1024) {
        int g = b * 14400 + i;
        w_bf[g] = f2bf(w[g]);
    }
    const float* cb = coords + (size_t)b * 3 * N;
    __shared__ float red[1024];
    float m[3];
    for (int d = 0; d < 3; ++d) {
        float s = 0.f;
        for (int n = tid; n < N; n += 1024) s += cb[d * N + n];
        red[tid] = s; __syncthreads();
        for (int w2 = 512; w2 > 0; w2 >>= 1) { if (tid < w2) red[tid] += red[tid + w2]; __syncthreads(); }
        m[d] = red[0] / (float)N;
        __syncthreads();
    }
    float mx = 0.f;
    for (int n = tid; n < N; n += 1024) {
        float dx = cb[0 * N + n] - m[0];
        float dy = cb[1 * N + n] - m[1];
        float dz = cb[2 * N + n] - m[2];
        mx = fmaxf(mx, dx * dx + dy * dy + dz * dz);
    }
    red[tid] = mx; __syncthreads();
    for (int w2 = 512; w2 > 0; w2 >>= 1) { if (tid < w2) red[tid] = fmaxf(red[tid], red[tid + w2]); __syncthreads(); }
    if (tid == 0) {
        stats[b * 4 + 0] = m[0];
        stats[b * 4 + 1] = m[1];
        stats[b * 4 + 2] = m[2];
        stats[b * 4 + 3] = 2.f * sqrtf(red[0]);
    }
}

// ---------- nc (output 2) + flat voxel idx + per-voxel histogram ----------
__global__ __launch_bounds__(256) void nc_idx_kernel(const float* __restrict__ coords,
                                                     const float* __restrict__ stats,
                                                     float* __restrict__ nc_out,
                                                     int* __restrict__ idxbuf,
                                                     int* __restrict__ hist) {
    int t = blockIdx.x * 256 + threadIdx.x;   // over B*N
    int b = t >> 14;
    int n = t & (N - 1);
    float denom = stats[b * 4 + 3];
    int v[3];
#pragma unroll
    for (int d = 0; d < 3; ++d) {
        float x = coords[((size_t)b * 3 + d) * N + n];
        float t0 = (x - stats[b * 4 + d]) / denom + 0.5f;
        t0 = t0 * (float)RR;
        t0 = fminf(fmaxf(t0, 0.f), (float)(RR - 1));
        nc_out[((size_t)b * 3 + d) * N + n] = t0;
        v[d] = (int)rintf(t0);   // round half to even == jnp.round
    }
    int iv = v[0] * (RR * RR) + v[1] * RR + v[2];
    idxbuf[t] = iv;
    atomicAdd(hist + b * V + iv, 1);
}

// ---------- exclusive prefix over V=32768 voxels per batch (int4 I/O) ----------
__global__ __launch_bounds__(1024) void prefix_kernel(const int* __restrict__ hist,
                                                      int* __restrict__ starts,
                                                      int* __restrict__ cursor) {
    __shared__ int part[1024];
    int b = blockIdx.x, t = threadIdx.x;
    int base = b * V + t * 32;
    const int4* hp = (const int4*)(hist + base);
    int4 h[8];
    int s = 0;
#pragma unroll
    for (int j = 0; j < 8; ++j) { h[j] = hp[j]; s += h[j].x + h[j].y + h[j].z + h[j].w; }
    part[t] = s; __syncthreads();
    for (int off = 1; off < 1024; off <<= 1) {
        int x = (t >= off) ? part[t - off] : 0;
        __syncthreads();
        part[t] += x;
        __syncthreads();
    }
    int run = part[t] - s;   // exclusive
    int4* sp = (int4*)(starts + base);
    int4* cp = (int4*)(cursor + base);
#pragma unroll
    for (int j = 0; j < 8; ++j) {
        int4 o;
        o.x = run; run += h[j].x;
        o.y = run; run += h[j].y;
        o.z = run; run += h[j].z;
        o.w = run; run += h[j].w;
        sp[j] = o; cp[j] = o;
    }
}

// ---------- scatter point ids into voxel-sorted order ----------
__global__ __launch_bounds__(256) void plist_kernel(const int* __restrict__ idxbuf,
                                                    int* __restrict__ cursor,
                                                    int* __restrict__ ptlist) {
    int t = blockIdx.x * 256 + threadIdx.x;   // over B*N
    int b = t >> 14;
    int n = t & (N - 1);
    int iv = idxbuf[t];
    int pos = atomicAdd(cursor + b * V + iv, 1);
    ptlist[(b << 14) + pos] = (n << 5) | (iv & 31);
}

// ---------- features [B][C][N] fp32 -> featT [B][N][C] bf16 ----------
// block = 32 n-rows x full 240 channels; stores are long contiguous runs,
// block output span = 15360 B (128B-aligned) -> no cross-block partial lines.
__global__ __launch_bounds__(256) void transpose_kernel(const float* __restrict__ feat,
                                                        unsigned short* __restrict__ featT) {
    __shared__ float t[C][33];
    int b = blockIdx.y;
    int n0 = blockIdx.x * 32;
    int l = threadIdx.x;
    const float* fb = feat + (size_t)b * C * N;
    unsigned short* fTb = featT + (size_t)b * N * C;
    int nl = l & 31, cs = l >> 5;   // 8 c-rows per pass
#pragma unroll
    for (int p = 0; p < 30; ++p) {
        int c = p * 8 + cs;
        t[c][nl] = fb[(size_t)c * N + n0 + nl];
    }
    __syncthreads();
    int ci = l & 127;               // uint (2-channel) index, <120 active
    int nh = l >> 7;                // 2 n-rows per pass
#pragma unroll
    for (int p = 0; p < 16; ++p) {
        int n = 2 * p + nh;
        if (ci < 120) {
            unsigned lo = f2bf(t[2 * ci][n]);
            unsigned hi = f2bf(t[2 * ci + 1][n]);
            *(unsigned*)&fTb[(size_t)(n0 + n) * C + 2 * ci] = lo | (hi << 16);
        }
    }
}

// ---------- fused per-column pipelined reduce + bf16 MFMA + BN + swish ----------
__global__ __launch_bounds__(256) void column_kernel(
    const unsigned short* __restrict__ featT,   // [B][N][C] bf16
    const int* __restrict__ ptlist,
    const int* __restrict__ starts,
    const int* __restrict__ hist,
    const unsigned short* __restrict__ w_bf,    // [240][480] bf16
    const float* __restrict__ cbias, const float* __restrict__ gamma,
    const float* __restrict__ beta, const float* __restrict__ mean,
    const float* __restrict__ var,
    float* __restrict__ out) {
    const int col = blockIdx.x, b = blockIdx.y;
    const int tid = threadIdx.x;
    const int v0 = col * 32;
    float* outb = out + (size_t)b * C * V;

    __shared__ float A_s[C], B_s[C];
    __shared__ unsigned short fea_s[32][FPAD];   // [z][k]: k<240 max, k>=240 avg (bf16)
    __shared__ int cnt_s[32];
    __shared__ int ebuf[EBUF];

    if (tid < C) {
        float sc = gamma[tid] * rsqrtf(var[tid] + 1e-5f);
        A_s[tid] = sc;
        B_s[tid] = (cbias[tid] - mean[tid]) * sc + beta[tid];
    }
    if (tid < 32) cnt_s[tid] = hist[b * V + v0 + tid];
    __syncthreads();

    int pc = 0;
#pragma unroll
    for (int z = 0; z < 32; ++z) pc += cnt_s[z];

    if (pc == 0) {   // empty column: constant output vector
        for (int i = tid; i < C * 32; i += 256) {
            int o = i >> 5, vv = i & 31;
            float y = B_s[o];
            y = y / (1.f + __expf(-y));
            outb[(size_t)o * V + v0 + vv] = y;
        }
        return;
    }

    // zero fea (covers empty voxels: max->0, avg->0)
    for (int i = tid; i < 32 * FPAD / 2; i += 256) ((unsigned*)fea_s)[i] = 0u;

    const int cu = tid;            // uint index: channels 2cu, 2cu+1
    const bool act = tid < 120;
    const int pos = starts[b * V + v0];
    const int* pl = ptlist + (b << 14) + pos;
    const unsigned short* fT = featT + (size_t)b * N * C;

    // ---- pipelined 2-channel stream over all points (sorted by z) ----
    float s0 = 0.f, s1 = 0.f, mx0 = -INFINITY, mx1 = -INFINITY;
    int curz = -1;
    for (int base = 0; base < pc; base += EBUF) {
        int mm = min(EBUF, pc - base);
        __syncthreads();
        for (int i = tid; i < mm; i += 256) ebuf[i] = pl[base + i];   // coalesced stage
        __syncthreads();
        if (act) {
            for (int i0 = 0; i0 < mm; i0 += 16) {
                int m = min(16, mm - i0);
                int e_[16];
#pragma unroll
                for (int j = 0; j < 16; ++j) e_[j] = ebuf[i0 + ((j < m) ? j : m - 1)];
                unsigned u_[16];
#pragma unroll
                for (int j = 0; j < 16; ++j)
                    u_[j] = *(const unsigned*)&fT[(size_t)(e_[j] >> 5) * C + 2 * cu];
#pragma unroll
                for (int j = 0; j < 16; ++j) {
                    if (j < m) {
                        int zj = e_[j] & 31;             // block-uniform
                        if (zj != curz) {                // uniform branch
                            if (curz >= 0) {
                                float k = (float)cnt_s[curz];
                                unsigned pm = (unsigned)f2bf(mx0) | ((unsigned)f2bf(mx1) << 16);
                                unsigned pa = (unsigned)f2bf(s0 / k) | ((unsigned)f2bf(s1 / k) << 16);
                                *(unsigned*)&fea_s[curz][2 * cu] = pm;
                                *(unsigned*)&fea_s[curz][C + 2 * cu] = pa;
                            }
                            curz = zj; s0 = s1 = 0.f; mx0 = mx1 = -INFINITY;
                        }
                        float lo = __uint_as_float(u_[j] << 16);
                        float hi = __uint_as_float(u_[j] & 0xffff0000u);
                        s0 += lo; s1 += hi;
                        mx0 = fmaxf(mx0, lo); mx1 = fmaxf(mx1, hi);
                    }
                }
            }
        }
    }
    if (act && curz >= 0) {
        float k = (float)cnt_s[curz];
        *(unsigned*)&fea_s[curz][2 * cu] = (unsigned)f2bf(mx0) | ((unsigned)f2bf(mx1) << 16);
        *(unsigned*)&fea_s[curz][C + 2 * cu] = (unsigned)f2bf(s0 / k) | ((unsigned)f2bf(s1 / k) << 16);
    }
    __syncthreads();

    // ---- MFMA: D[o][z] = sum_k w[o][k] * fea[z][k] ----
    const int lane = tid & 63, wave = tid >> 6;
    const int nt = wave & 1;            // z half
    const int mbase = (wave >> 1) * 8;  // o-tile base (15 tiles of 16)
    const int mcnt = (wave >> 1) ? 7 : 8;
    const int zl = nt * 16 + (lane & 15);
    const int koff = (lane >> 4) * 8;

    f32x4 acc[8];
#pragma unroll
    for (int i = 0; i < 8; ++i) acc[i] = (f32x4){0.f, 0.f, 0.f, 0.f};

#pragma unroll
    for (int kc = 0; kc < 15; ++kc) {
        const int kg = kc * 32 + koff;
        bf16x8 bfr = *(const bf16x8*)&fea_s[zl][kg];
        const unsigned short* wp = w_bf + (size_t)(mbase * 16 + (lane & 15)) * K2C + kg;
#pragma unroll
        for (int mt = 0; mt < 8; ++mt) {
            if (mt < mcnt) {
                bf16x8 afr = *(const bf16x8*)(wp + (size_t)mt * 16 * K2C);
                acc[mt] = __builtin_amdgcn_mfma_f32_16x16x32_bf16(afr, bfr, acc[mt], 0, 0, 0);
            }
        }
    }

    const int vv = v0 + zl;
    const int rbase = (lane >> 4) * 4;
#pragma unroll
    for (int mt = 0; mt < 8; ++mt) {
        if (mt < mcnt) {
#pragma unroll
            for (int r = 0; r < 4; ++r) {
                int o = (mbase + mt) * 16 + rbase + r;
                float y = acc[mt][r] * A_s[o] + B_s[o];
                y = y / (1.f + __expf(-y));
                outb[(size_t)o * V + vv] = y;
            }
        }
    }
}

extern "C" void kernel_launch(void* const* d_in, const int* in_sizes, int n_in,
                              void* d_out, int out_size, void* d_ws, size_t ws_size,
                              hipStream_t stream) {
    const float* features = (const float*)d_in[0];  // [B][C][N]
    const float* coords   = (const float*)d_in[1];  // [B][3][N]
    const float* conv_w   = (const float*)d_in[2];  // [240][480]
    const float* conv_b   = (const float*)d_in[3];
    const float* gamma    = (const float*)d_in[4];
    const float* beta     = (const float*)d_in[5];
    const float* mean     = (const float*)d_in[6];
    const float* var      = (const float*)d_in[7];

    float* out    = (float*)d_out;                    // [B][C][V]
    float* nc_out = out + (size_t)B * C * V;          // [B][3][N]

    char* ws = (char*)d_ws;
    size_t off = 0;
    auto carve = [&](size_t bytes) { char* p = ws + off; off += (bytes + 255) & ~(size_t)255; return p; };
    int*            hist   = (int*)carve((size_t)B * V * 4);          // 1 MB
    float*          stats  = (float*)carve(B * 4 * 4);
    int*            idxbuf = (int*)carve((size_t)B * N * 4);
    int*            starts = (int*)carve((size_t)B * V * 4);
    int*            cursor = (int*)carve((size_t)B * V * 4);
    int*            ptlist = (int*)carve((size_t)B * N * 4);
    unsigned short* w_bf   = (unsigned short*)carve((size_t)C * K2C * 2);
    unsigned short* featT  = (unsigned short*)carve((size_t)B * N * C * 2);  // 63 MB
    (void)off;

    stats_kernel<<<B, 1024, 0, stream>>>(coords, stats, hist, conv_w, w_bf);
    nc_idx_kernel<<<(B * N) / 256, 256, 0, stream>>>(coords, stats, nc_out, idxbuf, hist);
    prefix_kernel<<<B, 1024, 0, stream>>>(hist, starts, cursor);
    plist_kernel<<<(B * N) / 256, 256, 0, stream>>>(idxbuf, cursor, ptlist);
    transpose_kernel<<<dim3(N / 32, B), 256, 0, stream>>>(features, featT);
    column_kernel<<<dim3(NCOL, B), 256, 0, stream>>>(
        featT, ptlist, starts, hist, w_bf,
        conv_b, gamma, beta, mean, var, out);
    (void)in_sizes; (void)n_in; (void)out_size;
}